// Round 9
// baseline (1327.891 us; speedup 1.0000x reference)
//
#include <hip/hip_runtime.h>
#include <hip/hip_bf16.h>
#include <stdint.h>

// Problem constants
#define BATCH 8
#define NSEQ  2048
#define EMB   768
#define NH    8
#define HD    96   // head dim

typedef unsigned short u16;
typedef __attribute__((ext_vector_type(8))) short short8;   // 8 x bf16 (4 VGPR)
typedef __attribute__((ext_vector_type(4))) float f32x4;
typedef __attribute__((ext_vector_type(16))) float f32x16;

static __device__ __forceinline__ u16 f2bf(float f) {
  union { float f; uint32_t u; } c{f};
  uint32_t u = c.u;
  return (u16)((u + 0x7FFFu + ((u >> 16) & 1u)) >> 16);  // RNE
}

// ---------------- x : f32 -> bf16 (vectorized) ----------------
__global__ __launch_bounds__(256) void k_convert_x(const float* __restrict__ x,
                                                   u16* __restrict__ xb) {
  size_t i = ((size_t)blockIdx.x * 256 + threadIdx.x) * 8;
  float4 a = *(const float4*)(x + i);
  float4 b = *(const float4*)(x + i + 4);
  short8 o;
  o[0] = f2bf(a.x); o[1] = f2bf(a.y); o[2] = f2bf(a.z); o[3] = f2bf(a.w);
  o[4] = f2bf(b.x); o[5] = f2bf(b.y); o[6] = f2bf(b.z); o[7] = f2bf(b.w);
  *(short8*)(xb + i) = o;
}

// ---------------- W [k][n] f32 -> WT [n][k] bf16 ----------------
__global__ __launch_bounds__(256) void k_wtrans(const float* __restrict__ Wq,
                                                const float* __restrict__ Wk,
                                                const float* __restrict__ Wv,
                                                const float* __restrict__ Wo,
                                                u16* __restrict__ WTall) {
  int z = blockIdx.z;
  const float* W = (z == 0) ? Wq : (z == 1) ? Wk : (z == 2) ? Wv : Wo;
  u16* WT = WTall + (size_t)z * EMB * EMB;
  __shared__ float tile[32][33];
  int o0 = blockIdx.x * 32, i0 = blockIdx.y * 32;
  int tx = threadIdx.x, ty = threadIdx.y;  // (32,8)
#pragma unroll
  for (int r = 0; r < 4; ++r)
    tile[ty * 4 + r][tx] = W[(size_t)(i0 + ty * 4 + r) * EMB + o0 + tx];
  __syncthreads();
#pragma unroll
  for (int r = 0; r < 4; ++r)
    WT[(size_t)(o0 + ty * 4 + r) * EMB + i0 + tx] = f2bf(tile[tx][ty * 4 + r]);
}

// ================= 256x256 8-phase GEMM (T2+T3+T4+T5) — unchanged, verified R4 =================
#define SBAR() do { __builtin_amdgcn_sched_barrier(0); __builtin_amdgcn_s_barrier(); } while (0)

#define MMA_QUAD(MFH, NFH, BF)                                                        \
  do {                                                                                \
    __builtin_amdgcn_s_setprio(1);                                                    \
    _Pragma("unroll") for (int mf2 = 0; mf2 < 4; ++mf2)                               \
      _Pragma("unroll") for (int nf2 = 0; nf2 < 2; ++nf2)                             \
        _Pragma("unroll") for (int ks = 0; ks < 2; ++ks)                              \
          acc[(MFH) * 4 + mf2][(NFH) * 2 + nf2] =                                     \
              __builtin_amdgcn_mfma_f32_16x16x32_bf16(                                \
                  af[mf2][ks], BF[nf2][ks],                                           \
                  acc[(MFH) * 4 + mf2][(NFH) * 2 + nf2], 0, 0, 0);                    \
    __builtin_amdgcn_s_setprio(0);                                                    \
  } while (0)

template <bool OUTF32>
static __device__ __forceinline__ void gemm256_body(const u16* __restrict__ Aop,
                                                    const u16* __restrict__ WT,
                                                    const float* __restrict__ bias,
                                                    void* __restrict__ out,
                                                    int m0, int n0, float oscale) {
  __shared__ u16 As[2][256 * 64];
  __shared__ u16 Bs[2][256 * 64];
  const int t = threadIdx.x;
  const int w = t >> 6, l = t & 63;
  const int lr = l & 15, lg = l >> 4;
  const int wr = w >> 2, wc = w & 3;
  const u16* PA = Aop + (size_t)m0 * EMB;
  const u16* PB = WT + (size_t)n0 * EMB;

  f32x4 acc[8][4] = {};
  short8 af[4][2], bfA[2][2], bfB[2][2];

  auto stage = [&](const u16* P, u16* lds, int kt, int i) {
    int gb = i * 512 + w * 64;           // wave-uniform granule base
    int g = gb + l;
    int row = g >> 3;
    int cb = ((g & 7) * 16) ^ ((row & 7) << 4);   // row is 128B => XOR closed
    const u16* src = P + (size_t)row * EMB + kt * 64 + (cb >> 1);
    __builtin_amdgcn_global_load_lds((const __attribute__((address_space(1))) void*)src,
                                     (__attribute__((address_space(3))) void*)(lds + gb * 8),
                                     16, 0, 0);
  };
  auto rdA = [&](const u16* lds, int mfh) {
#pragma unroll
    for (int mf2 = 0; mf2 < 4; ++mf2)
#pragma unroll
      for (int ks = 0; ks < 2; ++ks) {
        int row = wr * 128 + (mfh * 4 + mf2) * 16 + lr;
        int cb = (ks * 64 + lg * 16) ^ ((lr & 7) << 4);
        af[mf2][ks] = *(const short8*)(lds + row * 64 + (cb >> 1));
      }
  };
  auto rdB = [&](const u16* lds, int nfh, short8 (&bf)[2][2]) {
#pragma unroll
    for (int nf2 = 0; nf2 < 2; ++nf2)
#pragma unroll
      for (int ks = 0; ks < 2; ++ks) {
        int row = wc * 64 + (nfh * 2 + nf2) * 16 + lr;
        int cb = (ks * 64 + lg * 16) ^ ((lr & 7) << 4);
        bf[nf2][ks] = *(const short8*)(lds + row * 64 + (cb >> 1));
      }
  };

#pragma unroll
  for (int i = 0; i < 4; ++i) stage(PA, As[0], 0, i);
#pragma unroll
  for (int i = 0; i < 4; ++i) stage(PB, Bs[0], 0, i);
#pragma unroll
  for (int i = 0; i < 4; ++i) stage(PA, As[1], 1, i);
#pragma unroll
  for (int i = 0; i < 4; ++i) stage(PB, Bs[1], 1, i);
  asm volatile("s_waitcnt vmcnt(8)" ::: "memory");
  __builtin_amdgcn_s_barrier();

  for (int it = 0; it < 6; ++it) {
    const int kt0 = 2 * it;
    const bool nl = (it < 5);
    rdA(As[0], 0);
    rdB(Bs[0], 0, bfA);
    SBAR();
    MMA_QUAD(0, 0, bfA);
    SBAR();
    rdB(Bs[0], 1, bfB);
    SBAR();
    MMA_QUAD(0, 1, bfB);
    SBAR();
    rdA(As[0], 1);
    if (nl) { stage(PB, Bs[0], kt0 + 2, 0); stage(PB, Bs[0], kt0 + 2, 1); }
    SBAR();
    MMA_QUAD(1, 1, bfB);
    SBAR();
    if (nl) {
      stage(PB, Bs[0], kt0 + 2, 2); stage(PB, Bs[0], kt0 + 2, 3);
#pragma unroll
      for (int i = 0; i < 4; ++i) stage(PA, As[0], kt0 + 2, i);
    }
    SBAR();
    MMA_QUAD(1, 0, bfA);
    __builtin_amdgcn_sched_barrier(0);
    if (nl) asm volatile("s_waitcnt vmcnt(8)" ::: "memory");
    else    asm volatile("s_waitcnt vmcnt(0)" ::: "memory");
    __builtin_amdgcn_s_barrier();

    rdA(As[1], 0);
    rdB(Bs[1], 0, bfA);
    SBAR();
    MMA_QUAD(0, 0, bfA);
    SBAR();
    rdB(Bs[1], 1, bfB);
    SBAR();
    MMA_QUAD(0, 1, bfB);
    SBAR();
    rdA(As[1], 1);
    if (nl) { stage(PB, Bs[1], kt0 + 3, 0); stage(PB, Bs[1], kt0 + 3, 1); }
    SBAR();
    MMA_QUAD(1, 1, bfB);
    SBAR();
    if (nl) {
      stage(PB, Bs[1], kt0 + 3, 2); stage(PB, Bs[1], kt0 + 3, 3);
#pragma unroll
      for (int i = 0; i < 4; ++i) stage(PA, As[1], kt0 + 3, i);
    }
    SBAR();
    MMA_QUAD(1, 0, bfA);
    __builtin_amdgcn_sched_barrier(0);
    if (nl) asm volatile("s_waitcnt vmcnt(8)" ::: "memory");
    else    asm volatile("s_waitcnt vmcnt(0)" ::: "memory");
    __builtin_amdgcn_s_barrier();
  }

#pragma unroll
  for (int nf = 0; nf < 4; ++nf) {
    int col = n0 + wc * 64 + nf * 16 + lr;
    float bv = bias[col];
#pragma unroll
    for (int mf = 0; mf < 8; ++mf)
#pragma unroll
      for (int r = 0; r < 4; ++r) {
        int row = m0 + wr * 128 + mf * 16 + lg * 4 + r;
        float v = (acc[mf][nf][r] + bv) * oscale;
        if (OUTF32)
          ((float*)out)[(size_t)row * EMB + col] = v;
        else
          ((u16*)out)[(size_t)row * EMB + col] = f2bf(v);
      }
  }
}

__global__ __launch_bounds__(512, 2) void k_qkv_gemm(const u16* __restrict__ X,
                                                     const u16* __restrict__ WTall,
                                                     const float* __restrict__ bq,
                                                     const float* __restrict__ bk,
                                                     const float* __restrict__ bv,
                                                     u16* __restrict__ Q, u16* __restrict__ K,
                                                     u16* __restrict__ V) {
  int z = blockIdx.z;
  const u16* WT = WTall + (size_t)z * EMB * EMB;
  const float* bias = (z == 0) ? bq : (z == 1) ? bk : bv;
  u16* out = (z == 0) ? Q : (z == 1) ? K : V;
  float sc = (z == 0) ? 1.4426950408889634f : 1.0f;
  gemm256_body<false>(X, WT, bias, out, blockIdx.x * 256, blockIdx.y * 256, sc);
}

__global__ __launch_bounds__(512, 2) void k_out_gemm(const u16* __restrict__ AO,
                                                     const u16* __restrict__ WTo,
                                                     const float* __restrict__ bo,
                                                     float* __restrict__ out) {
  gemm256_body<true>(AO, WTo, bo, out, blockIdx.x * 256, blockIdx.y * 256, 1.0f);
}

// ---------------- V [B,N,E] slice -> VT [B*H, 96, 2048] ----------------
__global__ __launch_bounds__(256) void k_vtrans(const u16* __restrict__ V,
                                                u16* __restrict__ VT) {
  const int bh = blockIdx.y, b = bh >> 3, h = bh & 7;
  const int n0 = blockIdx.x * 128;
  __shared__ u16 LT[96][136];  // [d][n], padded
  const int t = threadIdx.x;
#pragma unroll
  for (int i = 0; i < 6; ++i) {
    int c = i * 256 + t;
    int n = c / 12, d8 = (c % 12) * 8;
    short8 v = *(const short8*)(V + ((size_t)(b * NSEQ + n0 + n)) * EMB + h * HD + d8);
#pragma unroll
    for (int j = 0; j < 8; ++j) LT[d8 + j][n] = (u16)v[j];
  }
  __syncthreads();
#pragma unroll
  for (int i = 0; i < 6; ++i) {
    int c = i * 256 + t;
    int d = c / 16, n8 = (c % 16) * 8;
    short8 v = *(const short8*)&LT[d][n8];
    *(short8*)(VT + ((size_t)bh * HD + d) * NSEQ + n0 + n8) = v;
  }
}

// ---- helpers for attention ----
static __device__ __forceinline__ void exp_sum(f32x16& s, float& ls) {
#pragma unroll
  for (int i = 0; i < 16; i += 4) {
    float e0, e1, e2, e3;
    asm("v_exp_f32 %0, %1" : "=v"(e0) : "v"(s[i + 0]));
    asm("v_exp_f32 %0, %1" : "=v"(e1) : "v"(s[i + 1]));
    asm("v_exp_f32 %0, %1" : "=v"(e2) : "v"(s[i + 2]));
    asm("v_exp_f32 %0, %1" : "=v"(e3) : "v"(s[i + 3]));
    s[i + 0] = e0; s[i + 1] = e1; s[i + 2] = e2; s[i + 3] = e3;
    ls += (e0 + e1) + (e2 + e3);
  }
}

template <int RB>
static __device__ __forceinline__ short8 pack_pa(const f32x16& s) {
  uint32_t w0, w1, w2, w3;
  asm("v_cvt_pk_bf16_f32 %0, %1, %2" : "=v"(w0) : "v"(s[RB + 0]), "v"(s[RB + 1]));
  asm("v_cvt_pk_bf16_f32 %0, %1, %2" : "=v"(w1) : "v"(s[RB + 2]), "v"(s[RB + 3]));
  asm("v_cvt_pk_bf16_f32 %0, %1, %2" : "=v"(w2) : "v"(s[RB + 4]), "v"(s[RB + 5]));
  asm("v_cvt_pk_bf16_f32 %0, %1, %2" : "=v"(w3) : "v"(s[RB + 6]), "v"(s[RB + 7]));
  asm("v_permlane32_swap_b32 %0, %1" : "+v"(w0), "+v"(w2));
  asm("v_permlane32_swap_b32 %0, %1" : "+v"(w1), "+v"(w3));
  union { uint32_t u[4]; short8 s8; } pu;
  pu.u[0] = w0; pu.u[1] = w1; pu.u[2] = w2; pu.u[3] = w3;
  return pu.s8;
}

// ---------------- flash attention (R8-verified compute), SINGLE-buffered LDS ----------------
// grid (64 bh, 8 q-tiles of 256), 256 thr = 4 waves x 64 q rows. KVBLK=64.
// LDS halved (27136 B) -> 4 blocks/CU (VGPR-capped) = 4 waves/SIMD for latency hiding.
// Two syncs/iter: compute(tile tt) -> sync -> write_tile(tt+1 from regs) -> sync.
__global__ __launch_bounds__(256, 4) void k_attn(const u16* __restrict__ Q,
                                                 const u16* __restrict__ K,
                                                 const u16* __restrict__ VT,
                                                 u16* __restrict__ AO) {
  __shared__ u16 Ks[64][104];   // [kv][d], 208B stride
  __shared__ u16 Vs[96][72];    // [d][kv], 144B stride
  const int t = threadIdx.x, w = t >> 6, l = t & 63;
  const int l31 = l & 31, hi = l >> 5;
  const int bh = blockIdx.x, b = bh >> 3, h = bh & 7;
  const int q0 = blockIdx.y * 256 + w * 64;   // wave owns q0..q0+63 (two 32-row subtiles)
  const size_t rowBase = (size_t)b * NSEQ;

  short8 qf0[6], qf1[6];
#pragma unroll
  for (int ksd = 0; ksd < 6; ++ksd) {
    qf0[ksd] = *(const short8*)(Q + (rowBase + q0 + l31) * EMB + h * HD + ksd * 16 + hi * 8);
    qf1[ksd] = *(const short8*)(Q + (rowBase + q0 + 32 + l31) * EMB + h * HD + ksd * 16 + hi * 8);
  }

  f32x16 oacc0[3] = {}, oacc1[3] = {};
  float ls0 = 0.f, ls1 = 0.f;

  short8 kr[3], vr[3];
  auto load_tile = [&](int kv0) {
#pragma unroll
    for (int i = 0; i < 3; ++i) {
      int c = i * 256 + t;
      int kn = c / 12, kd8 = (c % 12) * 8;
      kr[i] = *(const short8*)(K + (rowBase + kv0 + kn) * EMB + h * HD + kd8);
      int vd = c / 8, vn8 = (c % 8) * 8;
      vr[i] = *(const short8*)(VT + ((size_t)bh * HD + vd) * NSEQ + kv0 + vn8);
    }
  };
  auto write_tile = [&]() {
#pragma unroll
    for (int i = 0; i < 3; ++i) {
      int c = i * 256 + t;
      int kn = c / 12, kd8 = (c % 12) * 8;
      *(short8*)&Ks[kn][kd8] = kr[i];
      int vd = c / 8, vn8 = (c % 8) * 8;
      *(short8*)&Vs[vd][vn8] = vr[i];
    }
  };

  load_tile(0);
  write_tile();
  __syncthreads();

  for (int tt = 0; tt < 32; ++tt) {
    if (tt < 31) load_tile((tt + 1) * 64);   // issue next tile's loads early (regs free)

    // ---- phase A: kv rows 0..31 of this tile ----
    f32x16 s00 = {}, s01 = {};
    __builtin_amdgcn_s_setprio(1);
#pragma unroll
    for (int ksd = 0; ksd < 6; ++ksd) {
      short8 kf = *(const short8*)&Ks[l31][ksd * 16 + hi * 8];
      s00 = __builtin_amdgcn_mfma_f32_32x32x16_bf16(kf, qf0[ksd], s00, 0, 0, 0);
      s01 = __builtin_amdgcn_mfma_f32_32x32x16_bf16(kf, qf1[ksd], s01, 0, 0, 0);
    }
    __builtin_amdgcn_s_setprio(0);
    exp_sum(s00, ls0);
    exp_sum(s01, ls1);
    short8 paA00 = pack_pa<0>(s00), paA01 = pack_pa<8>(s00);
    short8 paA10 = pack_pa<0>(s01), paA11 = pack_pa<8>(s01);
    __builtin_amdgcn_s_setprio(1);
#pragma unroll
    for (int dt = 0; dt < 3; ++dt) {
      short8 vfa = *(const short8*)&Vs[dt * 32 + l31][hi * 8];
      short8 vfb = *(const short8*)&Vs[dt * 32 + l31][16 + hi * 8];
      oacc0[dt] = __builtin_amdgcn_mfma_f32_32x32x16_bf16(paA00, vfa, oacc0[dt], 0, 0, 0);
      oacc1[dt] = __builtin_amdgcn_mfma_f32_32x32x16_bf16(paA10, vfa, oacc1[dt], 0, 0, 0);
      oacc0[dt] = __builtin_amdgcn_mfma_f32_32x32x16_bf16(paA01, vfb, oacc0[dt], 0, 0, 0);
      oacc1[dt] = __builtin_amdgcn_mfma_f32_32x32x16_bf16(paA11, vfb, oacc1[dt], 0, 0, 0);
    }
    __builtin_amdgcn_s_setprio(0);

    // ---- phase B: kv rows 32..63 ----
    f32x16 s10 = {}, s11 = {};
    __builtin_amdgcn_s_setprio(1);
#pragma unroll
    for (int ksd = 0; ksd < 6; ++ksd) {
      short8 kf = *(const short8*)&Ks[32 + l31][ksd * 16 + hi * 8];
      s10 = __builtin_amdgcn_mfma_f32_32x32x16_bf16(kf, qf0[ksd], s10, 0, 0, 0);
      s11 = __builtin_amdgcn_mfma_f32_32x32x16_bf16(kf, qf1[ksd], s11, 0, 0, 0);
    }
    __builtin_amdgcn_s_setprio(0);
    exp_sum(s10, ls0);
    exp_sum(s11, ls1);
    short8 paB00 = pack_pa<0>(s10), paB01 = pack_pa<8>(s10);
    short8 paB10 = pack_pa<0>(s11), paB11 = pack_pa<8>(s11);
    __builtin_amdgcn_s_setprio(1);
#pragma unroll
    for (int dt = 0; dt < 3; ++dt) {
      short8 vfa = *(const short8*)&Vs[dt * 32 + l31][32 + hi * 8];
      short8 vfb = *(const short8*)&Vs[dt * 32 + l31][48 + hi * 8];
      oacc0[dt] = __builtin_amdgcn_mfma_f32_32x32x16_bf16(paB00, vfa, oacc0[dt], 0, 0, 0);
      oacc1[dt] = __builtin_amdgcn_mfma_f32_32x32x16_bf16(paB10, vfa, oacc1[dt], 0, 0, 0);
      oacc0[dt] = __builtin_amdgcn_mfma_f32_32x32x16_bf16(paB01, vfb, oacc0[dt], 0, 0, 0);
      oacc1[dt] = __builtin_amdgcn_mfma_f32_32x32x16_bf16(paB11, vfb, oacc1[dt], 0, 0, 0);
    }
    __builtin_amdgcn_s_setprio(0);

    __syncthreads();                 // all reads of tile tt done
    if (tt < 31) {
      write_tile();                  // tile tt+1 regs -> LDS
      __syncthreads();               // writes visible before next iter's reads
    }
  }

  // ---- epilogue: normalize by rowsum * sqrt(EMB), write bf16 ----
  ls0 += __shfl_xor(ls0, 32, 64);
  ls1 += __shfl_xor(ls1, 32, 64);
  float inv0 = 1.0f / (ls0 * 27.712812921102035f);
  float inv1 = 1.0f / (ls1 * 27.712812921102035f);
#pragma unroll
  for (int r = 0; r < 16; ++r) {
    int qreg = (r & 3) + 8 * (r >> 2) + 4 * hi;
    float iq0 = __shfl(inv0, qreg, 64);
    float iq1 = __shfl(inv1, qreg, 64);
#pragma unroll
    for (int dt = 0; dt < 3; ++dt) {
      AO[(rowBase + q0 + qreg) * EMB + h * HD + dt * 32 + l31] = f2bf(oacc0[dt][r] * iq0);
      AO[(rowBase + q0 + 32 + qreg) * EMB + h * HD + dt * 32 + l31] = f2bf(oacc1[dt][r] * iq1);
    }
  }
}

// ---------------- launch ----------------
extern "C" void kernel_launch(void* const* d_in, const int* in_sizes, int n_in,
                              void* d_out, int out_size, void* d_ws, size_t ws_size,
                              hipStream_t stream) {
  (void)in_sizes; (void)n_in; (void)out_size; (void)ws_size;
  const float* x  = (const float*)d_in[0];
  const float* Wq = (const float*)d_in[1];
  const float* bq = (const float*)d_in[2];
  const float* Wk = (const float*)d_in[3];
  const float* bk = (const float*)d_in[4];
  const float* Wv = (const float*)d_in[5];
  const float* bv = (const float*)d_in[6];
  const float* Wo = (const float*)d_in[7];
  const float* bo = (const float*)d_in[8];
  float* out = (float*)d_out;

  char* ws = (char*)d_ws;
  const size_t SZ = (size_t)BATCH * NSEQ * EMB * 2;  // bytes per bf16 activation buffer
  u16* XB = (u16*)(ws);            // x bf16; later reused as VT
  u16* QB = (u16*)(ws + SZ);
  u16* KB = (u16*)(ws + 2 * SZ);
  u16* VB = (u16*)(ws + 3 * SZ);   // later reused as attn_out
  u16* WT = (u16*)(ws + 4 * SZ);   // 4 x 768*768 bf16
  u16* VT = XB;
  u16* AO = VB;

  k_convert_x<<<dim3(6144), dim3(256), 0, stream>>>(x, XB);
  k_wtrans<<<dim3(24, 24, 4), dim3(32, 8), 0, stream>>>(Wq, Wk, Wv, Wo, WT);
  k_qkv_gemm<<<dim3(64, 3, 3), dim3(512), 0, stream>>>(XB, WT, bq, bk, bv, QB, KB, VB);
  k_vtrans<<<dim3(16, 64), dim3(256), 0, stream>>>(VB, VT);
  k_attn<<<dim3(64, 8), dim3(256), 0, stream>>>(QB, KB, VT, AO);
  k_out_gemm<<<dim3(64, 3), dim3(512), 0, stream>>>(AO, WT + (size_t)3 * EMB * EMB, bo, out);
}

// Round 10
// 241.605 us; speedup vs baseline: 5.4961x; 5.4961x over previous
//
#include <hip/hip_runtime.h>
#include <hip/hip_bf16.h>
#include <stdint.h>

// Problem constants
#define BATCH 8
#define NSEQ  2048
#define EMB   768
#define NH    8
#define HD    96   // head dim

typedef unsigned short u16;
typedef __attribute__((ext_vector_type(8))) short short8;   // 8 x bf16 (4 VGPR)
typedef __attribute__((ext_vector_type(4))) float f32x4;
typedef __attribute__((ext_vector_type(16))) float f32x16;

static __device__ __forceinline__ u16 f2bf(float f) {
  union { float f; uint32_t u; } c{f};
  uint32_t u = c.u;
  return (u16)((u + 0x7FFFu + ((u >> 16) & 1u)) >> 16);  // RNE
}

// ---------------- fused preprocess: x->bf16 (blocks 0..6143) + W->WT bf16 (blocks 6144..8447) ----
__global__ __launch_bounds__(256) void k_prep(const float* __restrict__ x,
                                              u16* __restrict__ xb,
                                              const float* __restrict__ Wq,
                                              const float* __restrict__ Wk,
                                              const float* __restrict__ Wv,
                                              const float* __restrict__ Wo,
                                              u16* __restrict__ WTall) {
  const int bid = blockIdx.x, t = threadIdx.x;
  if (bid < 6144) {
    size_t i = ((size_t)bid * 256 + t) * 8;
    float4 a = *(const float4*)(x + i);
    float4 b = *(const float4*)(x + i + 4);
    short8 o;
    o[0] = f2bf(a.x); o[1] = f2bf(a.y); o[2] = f2bf(a.z); o[3] = f2bf(a.w);
    o[4] = f2bf(b.x); o[5] = f2bf(b.y); o[6] = f2bf(b.z); o[7] = f2bf(b.w);
    *(short8*)(xb + i) = o;
  } else {
    const int id = bid - 6144;            // 0..2303 = 24*24*4
    const int z = id / 576, rem = id % 576;
    const int bx = rem % 24, by = rem / 24;
    const float* W = (z == 0) ? Wq : (z == 1) ? Wk : (z == 2) ? Wv : Wo;
    u16* WT = WTall + (size_t)z * EMB * EMB;
    __shared__ float tile[32][33];
    const int o0 = bx * 32, i0 = by * 32;
    const int tx = t & 31, ty = t >> 5;   // (32,8)
#pragma unroll
    for (int r = 0; r < 4; ++r)
      tile[ty * 4 + r][tx] = W[(size_t)(i0 + ty * 4 + r) * EMB + o0 + tx];
    __syncthreads();
#pragma unroll
    for (int r = 0; r < 4; ++r)
      WT[(size_t)(o0 + ty * 4 + r) * EMB + i0 + tx] = f2bf(tile[tx][ty * 4 + r]);
  }
}

// ================= 256x256 8-phase GEMM (T2+T3+T4+T5) — unchanged, verified R4/R8 =================
#define SBAR() do { __builtin_amdgcn_sched_barrier(0); __builtin_amdgcn_s_barrier(); } while (0)

#define MMA_QUAD(MFH, NFH, BF)                                                        \
  do {                                                                                \
    __builtin_amdgcn_s_setprio(1);                                                    \
    _Pragma("unroll") for (int mf2 = 0; mf2 < 4; ++mf2)                               \
      _Pragma("unroll") for (int nf2 = 0; nf2 < 2; ++nf2)                             \
        _Pragma("unroll") for (int ks = 0; ks < 2; ++ks)                              \
          acc[(MFH) * 4 + mf2][(NFH) * 2 + nf2] =                                     \
              __builtin_amdgcn_mfma_f32_16x16x32_bf16(                                \
                  af[mf2][ks], BF[nf2][ks],                                           \
                  acc[(MFH) * 4 + mf2][(NFH) * 2 + nf2], 0, 0, 0);                    \
    __builtin_amdgcn_s_setprio(0);                                                    \
  } while (0)

template <bool OUTF32>
static __device__ __forceinline__ void gemm256_body(const u16* __restrict__ Aop,
                                                    const u16* __restrict__ WT,
                                                    const float* __restrict__ bias,
                                                    void* __restrict__ out,
                                                    int m0, int n0, float oscale) {
  __shared__ u16 As[2][256 * 64];
  __shared__ u16 Bs[2][256 * 64];
  const int t = threadIdx.x;
  const int w = t >> 6, l = t & 63;
  const int lr = l & 15, lg = l >> 4;
  const int wr = w >> 2, wc = w & 3;
  const u16* PA = Aop + (size_t)m0 * EMB;
  const u16* PB = WT + (size_t)n0 * EMB;

  f32x4 acc[8][4] = {};
  short8 af[4][2], bfA[2][2], bfB[2][2];

  auto stage = [&](const u16* P, u16* lds, int kt, int i) {
    int gb = i * 512 + w * 64;           // wave-uniform granule base
    int g = gb + l;
    int row = g >> 3;
    int cb = ((g & 7) * 16) ^ ((row & 7) << 4);   // row is 128B => XOR closed
    const u16* src = P + (size_t)row * EMB + kt * 64 + (cb >> 1);
    __builtin_amdgcn_global_load_lds((const __attribute__((address_space(1))) void*)src,
                                     (__attribute__((address_space(3))) void*)(lds + gb * 8),
                                     16, 0, 0);
  };
  auto rdA = [&](const u16* lds, int mfh) {
#pragma unroll
    for (int mf2 = 0; mf2 < 4; ++mf2)
#pragma unroll
      for (int ks = 0; ks < 2; ++ks) {
        int row = wr * 128 + (mfh * 4 + mf2) * 16 + lr;
        int cb = (ks * 64 + lg * 16) ^ ((lr & 7) << 4);
        af[mf2][ks] = *(const short8*)(lds + row * 64 + (cb >> 1));
      }
  };
  auto rdB = [&](const u16* lds, int nfh, short8 (&bf)[2][2]) {
#pragma unroll
    for (int nf2 = 0; nf2 < 2; ++nf2)
#pragma unroll
      for (int ks = 0; ks < 2; ++ks) {
        int row = wc * 64 + (nfh * 2 + nf2) * 16 + lr;
        int cb = (ks * 64 + lg * 16) ^ ((lr & 7) << 4);
        bf[nf2][ks] = *(const short8*)(lds + row * 64 + (cb >> 1));
      }
  };

#pragma unroll
  for (int i = 0; i < 4; ++i) stage(PA, As[0], 0, i);
#pragma unroll
  for (int i = 0; i < 4; ++i) stage(PB, Bs[0], 0, i);
#pragma unroll
  for (int i = 0; i < 4; ++i) stage(PA, As[1], 1, i);
#pragma unroll
  for (int i = 0; i < 4; ++i) stage(PB, Bs[1], 1, i);
  asm volatile("s_waitcnt vmcnt(8)" ::: "memory");
  __builtin_amdgcn_s_barrier();

  for (int it = 0; it < 6; ++it) {
    const int kt0 = 2 * it;
    const bool nl = (it < 5);
    rdA(As[0], 0);
    rdB(Bs[0], 0, bfA);
    SBAR();
    MMA_QUAD(0, 0, bfA);
    SBAR();
    rdB(Bs[0], 1, bfB);
    SBAR();
    MMA_QUAD(0, 1, bfB);
    SBAR();
    rdA(As[0], 1);
    if (nl) { stage(PB, Bs[0], kt0 + 2, 0); stage(PB, Bs[0], kt0 + 2, 1); }
    SBAR();
    MMA_QUAD(1, 1, bfB);
    SBAR();
    if (nl) {
      stage(PB, Bs[0], kt0 + 2, 2); stage(PB, Bs[0], kt0 + 2, 3);
#pragma unroll
      for (int i = 0; i < 4; ++i) stage(PA, As[0], kt0 + 2, i);
    }
    SBAR();
    MMA_QUAD(1, 0, bfA);
    __builtin_amdgcn_sched_barrier(0);
    if (nl) asm volatile("s_waitcnt vmcnt(8)" ::: "memory");
    else    asm volatile("s_waitcnt vmcnt(0)" ::: "memory");
    __builtin_amdgcn_s_barrier();

    rdA(As[1], 0);
    rdB(Bs[1], 0, bfA);
    SBAR();
    MMA_QUAD(0, 0, bfA);
    SBAR();
    rdB(Bs[1], 1, bfB);
    SBAR();
    MMA_QUAD(0, 1, bfB);
    SBAR();
    rdA(As[1], 1);
    if (nl) { stage(PB, Bs[1], kt0 + 3, 0); stage(PB, Bs[1], kt0 + 3, 1); }
    SBAR();
    MMA_QUAD(1, 1, bfB);
    SBAR();
    if (nl) {
      stage(PB, Bs[1], kt0 + 3, 2); stage(PB, Bs[1], kt0 + 3, 3);
#pragma unroll
      for (int i = 0; i < 4; ++i) stage(PA, As[1], kt0 + 3, i);
    }
    SBAR();
    MMA_QUAD(1, 0, bfA);
    __builtin_amdgcn_sched_barrier(0);
    if (nl) asm volatile("s_waitcnt vmcnt(8)" ::: "memory");
    else    asm volatile("s_waitcnt vmcnt(0)" ::: "memory");
    __builtin_amdgcn_s_barrier();
  }

#pragma unroll
  for (int nf = 0; nf < 4; ++nf) {
    int col = n0 + wc * 64 + nf * 16 + lr;
    float bv = bias[col];
#pragma unroll
    for (int mf = 0; mf < 8; ++mf)
#pragma unroll
      for (int r = 0; r < 4; ++r) {
        int row = m0 + wr * 128 + mf * 16 + lg * 4 + r;
        float v = (acc[mf][nf][r] + bv) * oscale;
        if (OUTF32)
          ((float*)out)[(size_t)row * EMB + col] = v;
        else
          ((u16*)out)[(size_t)row * EMB + col] = f2bf(v);
      }
  }
}

__global__ __launch_bounds__(512, 2) void k_qkv_gemm(const u16* __restrict__ X,
                                                     const u16* __restrict__ WTall,
                                                     const float* __restrict__ bq,
                                                     const float* __restrict__ bk,
                                                     const float* __restrict__ bv,
                                                     u16* __restrict__ Q, u16* __restrict__ K,
                                                     u16* __restrict__ V) {
  int z = blockIdx.z;
  const u16* WT = WTall + (size_t)z * EMB * EMB;
  const float* bias = (z == 0) ? bq : (z == 1) ? bk : bv;
  u16* out = (z == 0) ? Q : (z == 1) ? K : V;
  float sc = (z == 0) ? 1.4426950408889634f : 1.0f;
  gemm256_body<false>(X, WT, bias, out, blockIdx.x * 256, blockIdx.y * 256, sc);
}

__global__ __launch_bounds__(512, 2) void k_out_gemm(const u16* __restrict__ AO,
                                                     const u16* __restrict__ WTo,
                                                     const float* __restrict__ bo,
                                                     float* __restrict__ out) {
  gemm256_body<true>(AO, WTo, bo, out, blockIdx.x * 256, blockIdx.y * 256, 1.0f);
}

// ---------------- V [B,N,E] slice -> VT [B*H, 96, 2048] ----------------
__global__ __launch_bounds__(256) void k_vtrans(const u16* __restrict__ V,
                                                u16* __restrict__ VT) {
  const int bh = blockIdx.y, b = bh >> 3, h = bh & 7;
  const int n0 = blockIdx.x * 128;
  __shared__ u16 LT[96][136];  // [d][n], padded
  const int t = threadIdx.x;
#pragma unroll
  for (int i = 0; i < 6; ++i) {
    int c = i * 256 + t;
    int n = c / 12, d8 = (c % 12) * 8;
    short8 v = *(const short8*)(V + ((size_t)(b * NSEQ + n0 + n)) * EMB + h * HD + d8);
#pragma unroll
    for (int j = 0; j < 8; ++j) LT[d8 + j][n] = (u16)v[j];
  }
  __syncthreads();
#pragma unroll
  for (int i = 0; i < 6; ++i) {
    int c = i * 256 + t;
    int d = c / 16, n8 = (c % 16) * 8;
    short8 v = *(const short8*)&LT[d][n8];
    *(short8*)(VT + ((size_t)bh * HD + d) * NSEQ + n0 + n8) = v;
  }
}

// ---- helpers for attention ----
static __device__ __forceinline__ void exp_sum(f32x16& s, float& ls) {
#pragma unroll
  for (int i = 0; i < 16; i += 4) {
    float e0, e1, e2, e3;
    asm("v_exp_f32 %0, %1" : "=v"(e0) : "v"(s[i + 0]));
    asm("v_exp_f32 %0, %1" : "=v"(e1) : "v"(s[i + 1]));
    asm("v_exp_f32 %0, %1" : "=v"(e2) : "v"(s[i + 2]));
    asm("v_exp_f32 %0, %1" : "=v"(e3) : "v"(s[i + 3]));
    s[i + 0] = e0; s[i + 1] = e1; s[i + 2] = e2; s[i + 3] = e3;
    ls += (e0 + e1) + (e2 + e3);
  }
}

template <int RB>
static __device__ __forceinline__ short8 pack_pa(const f32x16& s) {
  uint32_t w0, w1, w2, w3;
  asm("v_cvt_pk_bf16_f32 %0, %1, %2" : "=v"(w0) : "v"(s[RB + 0]), "v"(s[RB + 1]));
  asm("v_cvt_pk_bf16_f32 %0, %1, %2" : "=v"(w1) : "v"(s[RB + 2]), "v"(s[RB + 3]));
  asm("v_cvt_pk_bf16_f32 %0, %1, %2" : "=v"(w2) : "v"(s[RB + 4]), "v"(s[RB + 5]));
  asm("v_cvt_pk_bf16_f32 %0, %1, %2" : "=v"(w3) : "v"(s[RB + 6]), "v"(s[RB + 7]));
  asm("v_permlane32_swap_b32 %0, %1" : "+v"(w0), "+v"(w2));
  asm("v_permlane32_swap_b32 %0, %1" : "+v"(w1), "+v"(w3));
  union { uint32_t u[4]; short8 s8; } pu;
  pu.u[0] = w0; pu.u[1] = w1; pu.u[2] = w2; pu.u[3] = w3;
  return pu.s8;
}

// ---------------- flash attention (R8-verified exact), bh-major grid for XCD/L2 locality ------
// grid (64 bh, 8 q-tiles of 256), 256 thr = 4 waves x 64 q rows. KVBLK=64, double-buffered.
// Occupancy is register-pinned: 128 VGPR + ~128 AGPR = 256/wave -> 8 waves/CU (2048-reg pool).
// Do NOT raise launch_bounds min-waves (R9: forced 128-total regalloc -> full spill, 11x slower).
__global__ __launch_bounds__(256, 2) void k_attn(const u16* __restrict__ Q,
                                                 const u16* __restrict__ K,
                                                 const u16* __restrict__ VT,
                                                 u16* __restrict__ AO) {
  __shared__ u16 Ks[2][64][104];   // [buf][kv][d], 208B stride
  __shared__ u16 Vs[2][96][72];    // [buf][d][kv], 144B stride
  const int t = threadIdx.x, w = t >> 6, l = t & 63;
  const int l31 = l & 31, hi = l >> 5;
  const int bh = blockIdx.x, b = bh >> 3, h = bh & 7;
  const int q0 = blockIdx.y * 256 + w * 64;   // wave owns q0..q0+63 (two 32-row subtiles)
  const size_t rowBase = (size_t)b * NSEQ;

  short8 qf0[6], qf1[6];
#pragma unroll
  for (int ksd = 0; ksd < 6; ++ksd) {
    qf0[ksd] = *(const short8*)(Q + (rowBase + q0 + l31) * EMB + h * HD + ksd * 16 + hi * 8);
    qf1[ksd] = *(const short8*)(Q + (rowBase + q0 + 32 + l31) * EMB + h * HD + ksd * 16 + hi * 8);
  }

  f32x16 oacc0[3] = {}, oacc1[3] = {};
  float ls0 = 0.f, ls1 = 0.f;

  short8 kr[3], vr[3];
  auto load_tile = [&](int kv0) {
#pragma unroll
    for (int i = 0; i < 3; ++i) {
      int c = i * 256 + t;
      int kn = c / 12, kd8 = (c % 12) * 8;
      kr[i] = *(const short8*)(K + (rowBase + kv0 + kn) * EMB + h * HD + kd8);
      int vd = c / 8, vn8 = (c % 8) * 8;
      vr[i] = *(const short8*)(VT + ((size_t)bh * HD + vd) * NSEQ + kv0 + vn8);
    }
  };
  auto write_tile = [&](int buf) {
#pragma unroll
    for (int i = 0; i < 3; ++i) {
      int c = i * 256 + t;
      int kn = c / 12, kd8 = (c % 12) * 8;
      *(short8*)&Ks[buf][kn][kd8] = kr[i];
      int vd = c / 8, vn8 = (c % 8) * 8;
      *(short8*)&Vs[buf][vd][vn8] = vr[i];
    }
  };

  load_tile(0);
  write_tile(0);
  load_tile(64);          // tile 1 in flight
  __syncthreads();

  for (int tt = 0; tt < 32; ++tt) {
    const int cur = tt & 1;
    if (tt < 31) write_tile(cur ^ 1);        // tile tt+1 (regs) -> other buffer
    if (tt < 30) load_tile((tt + 2) * 64);   // issue tile tt+2

    // ---- phase A: kv rows 0..31 of this tile ----
    f32x16 s00 = {}, s01 = {};
    __builtin_amdgcn_s_setprio(1);
#pragma unroll
    for (int ksd = 0; ksd < 6; ++ksd) {
      short8 kf = *(const short8*)&Ks[cur][l31][ksd * 16 + hi * 8];
      s00 = __builtin_amdgcn_mfma_f32_32x32x16_bf16(kf, qf0[ksd], s00, 0, 0, 0);
      s01 = __builtin_amdgcn_mfma_f32_32x32x16_bf16(kf, qf1[ksd], s01, 0, 0, 0);
    }
    __builtin_amdgcn_s_setprio(0);
    exp_sum(s00, ls0);
    exp_sum(s01, ls1);
    short8 paA00 = pack_pa<0>(s00), paA01 = pack_pa<8>(s00);
    short8 paA10 = pack_pa<0>(s01), paA11 = pack_pa<8>(s01);
    __builtin_amdgcn_s_setprio(1);
#pragma unroll
    for (int dt = 0; dt < 3; ++dt) {
      short8 vfa = *(const short8*)&Vs[cur][dt * 32 + l31][hi * 8];
      short8 vfb = *(const short8*)&Vs[cur][dt * 32 + l31][16 + hi * 8];
      oacc0[dt] = __builtin_amdgcn_mfma_f32_32x32x16_bf16(paA00, vfa, oacc0[dt], 0, 0, 0);
      oacc1[dt] = __builtin_amdgcn_mfma_f32_32x32x16_bf16(paA10, vfa, oacc1[dt], 0, 0, 0);
      oacc0[dt] = __builtin_amdgcn_mfma_f32_32x32x16_bf16(paA01, vfb, oacc0[dt], 0, 0, 0);
      oacc1[dt] = __builtin_amdgcn_mfma_f32_32x32x16_bf16(paA11, vfb, oacc1[dt], 0, 0, 0);
    }
    __builtin_amdgcn_s_setprio(0);

    // ---- phase B: kv rows 32..63 ----
    f32x16 s10 = {}, s11 = {};
    __builtin_amdgcn_s_setprio(1);
#pragma unroll
    for (int ksd = 0; ksd < 6; ++ksd) {
      short8 kf = *(const short8*)&Ks[cur][32 + l31][ksd * 16 + hi * 8];
      s10 = __builtin_amdgcn_mfma_f32_32x32x16_bf16(kf, qf0[ksd], s10, 0, 0, 0);
      s11 = __builtin_amdgcn_mfma_f32_32x32x16_bf16(kf, qf1[ksd], s11, 0, 0, 0);
    }
    __builtin_amdgcn_s_setprio(0);
    exp_sum(s10, ls0);
    exp_sum(s11, ls1);
    short8 paB00 = pack_pa<0>(s10), paB01 = pack_pa<8>(s10);
    short8 paB10 = pack_pa<0>(s11), paB11 = pack_pa<8>(s11);
    __builtin_amdgcn_s_setprio(1);
#pragma unroll
    for (int dt = 0; dt < 3; ++dt) {
      short8 vfa = *(const short8*)&Vs[cur][dt * 32 + l31][32 + hi * 8];
      short8 vfb = *(const short8*)&Vs[cur][dt * 32 + l31][48 + hi * 8];
      oacc0[dt] = __builtin_amdgcn_mfma_f32_32x32x16_bf16(paB00, vfa, oacc0[dt], 0, 0, 0);
      oacc1[dt] = __builtin_amdgcn_mfma_f32_32x32x16_bf16(paB10, vfa, oacc1[dt], 0, 0, 0);
      oacc0[dt] = __builtin_amdgcn_mfma_f32_32x32x16_bf16(paB01, vfb, oacc0[dt], 0, 0, 0);
      oacc1[dt] = __builtin_amdgcn_mfma_f32_32x32x16_bf16(paB11, vfb, oacc1[dt], 0, 0, 0);
    }
    __builtin_amdgcn_s_setprio(0);

    __syncthreads();
  }

  // ---- epilogue: normalize by rowsum * sqrt(EMB), write bf16 ----
  ls0 += __shfl_xor(ls0, 32, 64);
  ls1 += __shfl_xor(ls1, 32, 64);
  float inv0 = 1.0f / (ls0 * 27.712812921102035f);
  float inv1 = 1.0f / (ls1 * 27.712812921102035f);
#pragma unroll
  for (int r = 0; r < 16; ++r) {
    int qreg = (r & 3) + 8 * (r >> 2) + 4 * hi;
    float iq0 = __shfl(inv0, qreg, 64);
    float iq1 = __shfl(inv1, qreg, 64);
#pragma unroll
    for (int dt = 0; dt < 3; ++dt) {
      AO[(rowBase + q0 + qreg) * EMB + h * HD + dt * 32 + l31] = f2bf(oacc0[dt][r] * iq0);
      AO[(rowBase + q0 + 32 + qreg) * EMB + h * HD + dt * 32 + l31] = f2bf(oacc1[dt][r] * iq1);
    }
  }
}

// ---------------- launch ----------------
extern "C" void kernel_launch(void* const* d_in, const int* in_sizes, int n_in,
                              void* d_out, int out_size, void* d_ws, size_t ws_size,
                              hipStream_t stream) {
  (void)in_sizes; (void)n_in; (void)out_size; (void)ws_size;
  const float* x  = (const float*)d_in[0];
  const float* Wq = (const float*)d_in[1];
  const float* bq = (const float*)d_in[2];
  const float* Wk = (const float*)d_in[3];
  const float* bk = (const float*)d_in[4];
  const float* Wv = (const float*)d_in[5];
  const float* bv = (const float*)d_in[6];
  const float* Wo = (const float*)d_in[7];
  const float* bo = (const float*)d_in[8];
  float* out = (float*)d_out;

  char* ws = (char*)d_ws;
  const size_t SZ = (size_t)BATCH * NSEQ * EMB * 2;  // bytes per bf16 activation buffer
  u16* XB = (u16*)(ws);            // x bf16; later reused as VT
  u16* QB = (u16*)(ws + SZ);
  u16* KB = (u16*)(ws + 2 * SZ);
  u16* VB = (u16*)(ws + 3 * SZ);   // later reused as attn_out
  u16* WT = (u16*)(ws + 4 * SZ);   // 4 x 768*768 bf16
  u16* VT = XB;
  u16* AO = VB;

  k_prep<<<dim3(6144 + 2304), dim3(256), 0, stream>>>(x, XB, Wq, Wk, Wv, Wo, WT);
  k_qkv_gemm<<<dim3(64, 3, 3), dim3(512), 0, stream>>>(XB, WT, bq, bk, bv, QB, KB, VB);
  k_vtrans<<<dim3(16, 64), dim3(256), 0, stream>>>(VB, VT);
  k_attn<<<dim3(64, 8), dim3(256), 0, stream>>>(QB, KB, VT, AO);
  k_out_gemm<<<dim3(64, 3), dim3(512), 0, stream>>>(AO, WT + (size_t)3 * EMB * EMB, bo, out);
}

// Round 12
// 241.350 us; speedup vs baseline: 5.5019x; 1.0011x over previous
//
#include <hip/hip_runtime.h>
#include <hip/hip_bf16.h>
#include <stdint.h>

// Problem constants
#define BATCH 8
#define NSEQ  2048
#define EMB   768
#define NH    8
#define HD    96   // head dim

typedef unsigned short u16;
typedef __attribute__((ext_vector_type(8))) short short8;   // 8 x bf16 (4 VGPR)
typedef __attribute__((ext_vector_type(4))) float f32x4;
typedef __attribute__((ext_vector_type(16))) float f32x16;

static __device__ __forceinline__ u16 f2bf(float f) {
  union { float f; uint32_t u; } c{f};
  uint32_t u = c.u;
  return (u16)((u + 0x7FFFu + ((u >> 16) & 1u)) >> 16);  // RNE
}

// ---------------- fused preprocess: x->bf16 (blocks 0..6143) + W->WT bf16 (blocks 6144..8447) ----
__global__ __launch_bounds__(256) void k_prep(const float* __restrict__ x,
                                              u16* __restrict__ xb,
                                              const float* __restrict__ Wq,
                                              const float* __restrict__ Wk,
                                              const float* __restrict__ Wv,
                                              const float* __restrict__ Wo,
                                              u16* __restrict__ WTall) {
  const int bid = blockIdx.x, t = threadIdx.x;
  if (bid < 6144) {
    size_t i = ((size_t)bid * 256 + t) * 8;
    float4 a = *(const float4*)(x + i);
    float4 b = *(const float4*)(x + i + 4);
    short8 o;
    o[0] = f2bf(a.x); o[1] = f2bf(a.y); o[2] = f2bf(a.z); o[3] = f2bf(a.w);
    o[4] = f2bf(b.x); o[5] = f2bf(b.y); o[6] = f2bf(b.z); o[7] = f2bf(b.w);
    *(short8*)(xb + i) = o;
  } else {
    const int id = bid - 6144;            // 0..2303 = 24*24*4
    const int z = id / 576, rem = id % 576;
    const int bx = rem % 24, by = rem / 24;
    const float* W = (z == 0) ? Wq : (z == 1) ? Wk : (z == 2) ? Wv : Wo;
    u16* WT = WTall + (size_t)z * EMB * EMB;
    __shared__ float tile[32][33];
    const int o0 = bx * 32, i0 = by * 32;
    const int tx = t & 31, ty = t >> 5;   // (32,8)
#pragma unroll
    for (int r = 0; r < 4; ++r)
      tile[ty * 4 + r][tx] = W[(size_t)(i0 + ty * 4 + r) * EMB + o0 + tx];
    __syncthreads();
#pragma unroll
    for (int r = 0; r < 4; ++r)
      WT[(size_t)(o0 + ty * 4 + r) * EMB + i0 + tx] = f2bf(tile[tx][ty * 4 + r]);
  }
}

// ================= 256x256 8-phase GEMM (T2+T3+T4+T5) — unchanged, verified R4/R8 =================
#define SBAR() do { __builtin_amdgcn_sched_barrier(0); __builtin_amdgcn_s_barrier(); } while (0)

#define MMA_QUAD(MFH, NFH, BF)                                                        \
  do {                                                                                \
    __builtin_amdgcn_s_setprio(1);                                                    \
    _Pragma("unroll") for (int mf2 = 0; mf2 < 4; ++mf2)                               \
      _Pragma("unroll") for (int nf2 = 0; nf2 < 2; ++nf2)                             \
        _Pragma("unroll") for (int ks = 0; ks < 2; ++ks)                              \
          acc[(MFH) * 4 + mf2][(NFH) * 2 + nf2] =                                     \
              __builtin_amdgcn_mfma_f32_16x16x32_bf16(                                \
                  af[mf2][ks], BF[nf2][ks],                                           \
                  acc[(MFH) * 4 + mf2][(NFH) * 2 + nf2], 0, 0, 0);                    \
    __builtin_amdgcn_s_setprio(0);                                                    \
  } while (0)

template <bool OUTF32>
static __device__ __forceinline__ void gemm256_body(const u16* __restrict__ Aop,
                                                    const u16* __restrict__ WT,
                                                    const float* __restrict__ bias,
                                                    void* __restrict__ out,
                                                    int m0, int n0, float oscale) {
  __shared__ u16 As[2][256 * 64];
  __shared__ u16 Bs[2][256 * 64];
  const int t = threadIdx.x;
  const int w = t >> 6, l = t & 63;
  const int lr = l & 15, lg = l >> 4;
  const int wr = w >> 2, wc = w & 3;
  const u16* PA = Aop + (size_t)m0 * EMB;
  const u16* PB = WT + (size_t)n0 * EMB;

  f32x4 acc[8][4] = {};
  short8 af[4][2], bfA[2][2], bfB[2][2];

  auto stage = [&](const u16* P, u16* lds, int kt, int i) {
    int gb = i * 512 + w * 64;           // wave-uniform granule base
    int g = gb + l;
    int row = g >> 3;
    int cb = ((g & 7) * 16) ^ ((row & 7) << 4);   // row is 128B => XOR closed
    const u16* src = P + (size_t)row * EMB + kt * 64 + (cb >> 1);
    __builtin_amdgcn_global_load_lds((const __attribute__((address_space(1))) void*)src,
                                     (__attribute__((address_space(3))) void*)(lds + gb * 8),
                                     16, 0, 0);
  };
  auto rdA = [&](const u16* lds, int mfh) {
#pragma unroll
    for (int mf2 = 0; mf2 < 4; ++mf2)
#pragma unroll
      for (int ks = 0; ks < 2; ++ks) {
        int row = wr * 128 + (mfh * 4 + mf2) * 16 + lr;
        int cb = (ks * 64 + lg * 16) ^ ((lr & 7) << 4);
        af[mf2][ks] = *(const short8*)(lds + row * 64 + (cb >> 1));
      }
  };
  auto rdB = [&](const u16* lds, int nfh, short8 (&bf)[2][2]) {
#pragma unroll
    for (int nf2 = 0; nf2 < 2; ++nf2)
#pragma unroll
      for (int ks = 0; ks < 2; ++ks) {
        int row = wc * 64 + (nfh * 2 + nf2) * 16 + lr;
        int cb = (ks * 64 + lg * 16) ^ ((lr & 7) << 4);
        bf[nf2][ks] = *(const short8*)(lds + row * 64 + (cb >> 1));
      }
  };

#pragma unroll
  for (int i = 0; i < 4; ++i) stage(PA, As[0], 0, i);
#pragma unroll
  for (int i = 0; i < 4; ++i) stage(PB, Bs[0], 0, i);
#pragma unroll
  for (int i = 0; i < 4; ++i) stage(PA, As[1], 1, i);
#pragma unroll
  for (int i = 0; i < 4; ++i) stage(PB, Bs[1], 1, i);
  asm volatile("s_waitcnt vmcnt(8)" ::: "memory");
  __builtin_amdgcn_s_barrier();

  for (int it = 0; it < 6; ++it) {
    const int kt0 = 2 * it;
    const bool nl = (it < 5);
    rdA(As[0], 0);
    rdB(Bs[0], 0, bfA);
    SBAR();
    MMA_QUAD(0, 0, bfA);
    SBAR();
    rdB(Bs[0], 1, bfB);
    SBAR();
    MMA_QUAD(0, 1, bfB);
    SBAR();
    rdA(As[0], 1);
    if (nl) { stage(PB, Bs[0], kt0 + 2, 0); stage(PB, Bs[0], kt0 + 2, 1); }
    SBAR();
    MMA_QUAD(1, 1, bfB);
    SBAR();
    if (nl) {
      stage(PB, Bs[0], kt0 + 2, 2); stage(PB, Bs[0], kt0 + 2, 3);
#pragma unroll
      for (int i = 0; i < 4; ++i) stage(PA, As[0], kt0 + 2, i);
    }
    SBAR();
    MMA_QUAD(1, 0, bfA);
    __builtin_amdgcn_sched_barrier(0);
    if (nl) asm volatile("s_waitcnt vmcnt(8)" ::: "memory");
    else    asm volatile("s_waitcnt vmcnt(0)" ::: "memory");
    __builtin_amdgcn_s_barrier();

    rdA(As[1], 0);
    rdB(Bs[1], 0, bfA);
    SBAR();
    MMA_QUAD(0, 0, bfA);
    SBAR();
    rdB(Bs[1], 1, bfB);
    SBAR();
    MMA_QUAD(0, 1, bfB);
    SBAR();
    rdA(As[1], 1);
    if (nl) { stage(PB, Bs[1], kt0 + 3, 0); stage(PB, Bs[1], kt0 + 3, 1); }
    SBAR();
    MMA_QUAD(1, 1, bfB);
    SBAR();
    if (nl) {
      stage(PB, Bs[1], kt0 + 3, 2); stage(PB, Bs[1], kt0 + 3, 3);
#pragma unroll
      for (int i = 0; i < 4; ++i) stage(PA, As[1], kt0 + 3, i);
    }
    SBAR();
    MMA_QUAD(1, 0, bfA);
    __builtin_amdgcn_sched_barrier(0);
    if (nl) asm volatile("s_waitcnt vmcnt(8)" ::: "memory");
    else    asm volatile("s_waitcnt vmcnt(0)" ::: "memory");
    __builtin_amdgcn_s_barrier();
  }

#pragma unroll
  for (int nf = 0; nf < 4; ++nf) {
    int col = n0 + wc * 64 + nf * 16 + lr;
    float bv = bias[col];
#pragma unroll
    for (int mf = 0; mf < 8; ++mf)
#pragma unroll
      for (int r = 0; r < 4; ++r) {
        int row = m0 + wr * 128 + mf * 16 + lg * 4 + r;
        float v = (acc[mf][nf][r] + bv) * oscale;
        if (OUTF32)
          ((float*)out)[(size_t)row * EMB + col] = v;
        else
          ((u16*)out)[(size_t)row * EMB + col] = f2bf(v);
      }
  }
}

__global__ __launch_bounds__(512, 2) void k_qkv_gemm(const u16* __restrict__ X,
                                                     const u16* __restrict__ WTall,
                                                     const float* __restrict__ bq,
                                                     const float* __restrict__ bk,
                                                     const float* __restrict__ bv,
                                                     u16* __restrict__ Q, u16* __restrict__ K,
                                                     u16* __restrict__ V) {
  int z = blockIdx.z;
  const u16* WT = WTall + (size_t)z * EMB * EMB;
  const float* bias = (z == 0) ? bq : (z == 1) ? bk : bv;
  u16* out = (z == 0) ? Q : (z == 1) ? K : V;
  float sc = (z == 0) ? 1.4426950408889634f : 1.0f;
  gemm256_body<false>(X, WT, bias, out, blockIdx.x * 256, blockIdx.y * 256, sc);
}

__global__ __launch_bounds__(512, 2) void k_out_gemm(const u16* __restrict__ AO,
                                                     const u16* __restrict__ WTo,
                                                     const float* __restrict__ bo,
                                                     float* __restrict__ out) {
  gemm256_body<true>(AO, WTo, bo, out, blockIdx.x * 256, blockIdx.y * 256, 1.0f);
}

// ---------------- V [B,N,E] slice -> VT [B*H, 96, 2048] ----------------
__global__ __launch_bounds__(256) void k_vtrans(const u16* __restrict__ V,
                                                u16* __restrict__ VT) {
  const int bh = blockIdx.y, b = bh >> 3, h = bh & 7;
  const int n0 = blockIdx.x * 128;
  __shared__ u16 LT[96][136];  // [d][n], padded
  const int t = threadIdx.x;
#pragma unroll
  for (int i = 0; i < 6; ++i) {
    int c = i * 256 + t;
    int n = c / 12, d8 = (c % 12) * 8;
    short8 v = *(const short8*)(V + ((size_t)(b * NSEQ + n0 + n)) * EMB + h * HD + d8);
#pragma unroll
    for (int j = 0; j < 8; ++j) LT[d8 + j][n] = (u16)v[j];
  }
  __syncthreads();
#pragma unroll
  for (int i = 0; i < 6; ++i) {
    int c = i * 256 + t;
    int d = c / 16, n8 = (c % 16) * 8;
    short8 v = *(const short8*)&LT[d][n8];
    *(short8*)(VT + ((size_t)bh * HD + d) * NSEQ + n0 + n8) = v;
  }
}

// ---- helpers for attention ----
static __device__ __forceinline__ void exp_sum(f32x16& s, float& ls) {
#pragma unroll
  for (int i = 0; i < 16; i += 4) {
    float e0, e1, e2, e3;
    asm("v_exp_f32 %0, %1" : "=v"(e0) : "v"(s[i + 0]));
    asm("v_exp_f32 %0, %1" : "=v"(e1) : "v"(s[i + 1]));
    asm("v_exp_f32 %0, %1" : "=v"(e2) : "v"(s[i + 2]));
    asm("v_exp_f32 %0, %1" : "=v"(e3) : "v"(s[i + 3]));
    s[i + 0] = e0; s[i + 1] = e1; s[i + 2] = e2; s[i + 3] = e3;
    ls += (e0 + e1) + (e2 + e3);
  }
}

template <int RB>
static __device__ __forceinline__ short8 pack_pa(const f32x16& s) {
  uint32_t w0, w1, w2, w3;
  asm("v_cvt_pk_bf16_f32 %0, %1, %2" : "=v"(w0) : "v"(s[RB + 0]), "v"(s[RB + 1]));
  asm("v_cvt_pk_bf16_f32 %0, %1, %2" : "=v"(w1) : "v"(s[RB + 2]), "v"(s[RB + 3]));
  asm("v_cvt_pk_bf16_f32 %0, %1, %2" : "=v"(w2) : "v"(s[RB + 4]), "v"(s[RB + 5]));
  asm("v_cvt_pk_bf16_f32 %0, %1, %2" : "=v"(w3) : "v"(s[RB + 6]), "v"(s[RB + 7]));
  asm("v_permlane32_swap_b32 %0, %1" : "+v"(w0), "+v"(w2));
  asm("v_permlane32_swap_b32 %0, %1" : "+v"(w1), "+v"(w3));
  union { uint32_t u[4]; short8 s8; } pu;
  pu.u[0] = w0; pu.u[1] = w1; pu.u[2] = w2; pu.u[3] = w3;
  return pu.s8;
}

// ---------------- flash attention (R8-verified exact), bh-major grid for XCD/L2 locality ------
// grid (64 bh, 8 q-tiles of 256), 256 thr = 4 waves x 64 q rows. KVBLK=64, double-buffered.
// Occupancy is register-pinned: 128 VGPR + ~128 AGPR = 256/wave -> 8 waves/CU (2048-reg pool).
// Do NOT raise launch_bounds min-waves (R9: forced 128-total regalloc -> full spill, 11x slower).
// Do NOT reorder staging (R6/R7/R11: three schedule variants all failed correctness).
__global__ __launch_bounds__(256, 2) void k_attn(const u16* __restrict__ Q,
                                                 const u16* __restrict__ K,
                                                 const u16* __restrict__ VT,
                                                 u16* __restrict__ AO) {
  __shared__ u16 Ks[2][64][104];   // [buf][kv][d], 208B stride
  __shared__ u16 Vs[2][96][72];    // [buf][d][kv], 144B stride
  const int t = threadIdx.x, w = t >> 6, l = t & 63;
  const int l31 = l & 31, hi = l >> 5;
  const int bh = blockIdx.x, b = bh >> 3, h = bh & 7;
  const int q0 = blockIdx.y * 256 + w * 64;   // wave owns q0..q0+63 (two 32-row subtiles)
  const size_t rowBase = (size_t)b * NSEQ;

  short8 qf0[6], qf1[6];
#pragma unroll
  for (int ksd = 0; ksd < 6; ++ksd) {
    qf0[ksd] = *(const short8*)(Q + (rowBase + q0 + l31) * EMB + h * HD + ksd * 16 + hi * 8);
    qf1[ksd] = *(const short8*)(Q + (rowBase + q0 + 32 + l31) * EMB + h * HD + ksd * 16 + hi * 8);
  }

  f32x16 oacc0[3] = {}, oacc1[3] = {};
  float ls0 = 0.f, ls1 = 0.f;

  short8 kr[3], vr[3];
  auto load_tile = [&](int kv0) {
#pragma unroll
    for (int i = 0; i < 3; ++i) {
      int c = i * 256 + t;
      int kn = c / 12, kd8 = (c % 12) * 8;
      kr[i] = *(const short8*)(K + (rowBase + kv0 + kn) * EMB + h * HD + kd8);
      int vd = c / 8, vn8 = (c % 8) * 8;
      vr[i] = *(const short8*)(VT + ((size_t)bh * HD + vd) * NSEQ + kv0 + vn8);
    }
  };
  auto write_tile = [&](int buf) {
#pragma unroll
    for (int i = 0; i < 3; ++i) {
      int c = i * 256 + t;
      int kn = c / 12, kd8 = (c % 12) * 8;
      *(short8*)&Ks[buf][kn][kd8] = kr[i];
      int vd = c / 8, vn8 = (c % 8) * 8;
      *(short8*)&Vs[buf][vd][vn8] = vr[i];
    }
  };

  load_tile(0);
  write_tile(0);
  load_tile(64);          // tile 1 in flight
  __syncthreads();

  for (int tt = 0; tt < 32; ++tt) {
    const int cur = tt & 1;
    if (tt < 31) write_tile(cur ^ 1);        // tile tt+1 (regs) -> other buffer
    if (tt < 30) load_tile((tt + 2) * 64);   // issue tile tt+2

    // ---- phase A: kv rows 0..31 of this tile ----
    f32x16 s00 = {}, s01 = {};
    __builtin_amdgcn_s_setprio(1);
#pragma unroll
    for (int ksd = 0; ksd < 6; ++ksd) {
      short8 kf = *(const short8*)&Ks[cur][l31][ksd * 16 + hi * 8];
      s00 = __builtin_amdgcn_mfma_f32_32x32x16_bf16(kf, qf0[ksd], s00, 0, 0, 0);
      s01 = __builtin_amdgcn_mfma_f32_32x32x16_bf16(kf, qf1[ksd], s01, 0, 0, 0);
    }
    __builtin_amdgcn_s_setprio(0);
    exp_sum(s00, ls0);
    exp_sum(s01, ls1);
    short8 paA00 = pack_pa<0>(s00), paA01 = pack_pa<8>(s00);
    short8 paA10 = pack_pa<0>(s01), paA11 = pack_pa<8>(s01);
    __builtin_amdgcn_s_setprio(1);
#pragma unroll
    for (int dt = 0; dt < 3; ++dt) {
      short8 vfa = *(const short8*)&Vs[cur][dt * 32 + l31][hi * 8];
      short8 vfb = *(const short8*)&Vs[cur][dt * 32 + l31][16 + hi * 8];
      oacc0[dt] = __builtin_amdgcn_mfma_f32_32x32x16_bf16(paA00, vfa, oacc0[dt], 0, 0, 0);
      oacc1[dt] = __builtin_amdgcn_mfma_f32_32x32x16_bf16(paA10, vfa, oacc1[dt], 0, 0, 0);
      oacc0[dt] = __builtin_amdgcn_mfma_f32_32x32x16_bf16(paA01, vfb, oacc0[dt], 0, 0, 0);
      oacc1[dt] = __builtin_amdgcn_mfma_f32_32x32x16_bf16(paA11, vfb, oacc1[dt], 0, 0, 0);
    }
    __builtin_amdgcn_s_setprio(0);

    // ---- phase B: kv rows 32..63 ----
    f32x16 s10 = {}, s11 = {};
    __builtin_amdgcn_s_setprio(1);
#pragma unroll
    for (int ksd = 0; ksd < 6; ++ksd) {
      short8 kf = *(const short8*)&Ks[cur][32 + l31][ksd * 16 + hi * 8];
      s10 = __builtin_amdgcn_mfma_f32_32x32x16_bf16(kf, qf0[ksd], s10, 0, 0, 0);
      s11 = __builtin_amdgcn_mfma_f32_32x32x16_bf16(kf, qf1[ksd], s11, 0, 0, 0);
    }
    __builtin_amdgcn_s_setprio(0);
    exp_sum(s10, ls0);
    exp_sum(s11, ls1);
    short8 paB00 = pack_pa<0>(s10), paB01 = pack_pa<8>(s10);
    short8 paB10 = pack_pa<0>(s11), paB11 = pack_pa<8>(s11);
    __builtin_amdgcn_s_setprio(1);
#pragma unroll
    for (int dt = 0; dt < 3; ++dt) {
      short8 vfa = *(const short8*)&Vs[cur][dt * 32 + l31][32 + hi * 8];
      short8 vfb = *(const short8*)&Vs[cur][dt * 32 + l31][48 + hi * 8];
      oacc0[dt] = __builtin_amdgcn_mfma_f32_32x32x16_bf16(paB00, vfa, oacc0[dt], 0, 0, 0);
      oacc1[dt] = __builtin_amdgcn_mfma_f32_32x32x16_bf16(paB10, vfa, oacc1[dt], 0, 0, 0);
      oacc0[dt] = __builtin_amdgcn_mfma_f32_32x32x16_bf16(paB01, vfb, oacc0[dt], 0, 0, 0);
      oacc1[dt] = __builtin_amdgcn_mfma_f32_32x32x16_bf16(paB11, vfb, oacc1[dt], 0, 0, 0);
    }
    __builtin_amdgcn_s_setprio(0);

    __syncthreads();
  }

  // ---- epilogue: normalize by rowsum * sqrt(EMB), write bf16 ----
  ls0 += __shfl_xor(ls0, 32, 64);
  ls1 += __shfl_xor(ls1, 32, 64);
  float inv0 = 1.0f / (ls0 * 27.712812921102035f);
  float inv1 = 1.0f / (ls1 * 27.712812921102035f);
#pragma unroll
  for (int r = 0; r < 16; ++r) {
    int qreg = (r & 3) + 8 * (r >> 2) + 4 * hi;
    float iq0 = __shfl(inv0, qreg, 64);
    float iq1 = __shfl(inv1, qreg, 64);
#pragma unroll
    for (int dt = 0; dt < 3; ++dt) {
      AO[(rowBase + q0 + qreg) * EMB + h * HD + dt * 32 + l31] = f2bf(oacc0[dt][r] * iq0);
      AO[(rowBase + q0 + 32 + qreg) * EMB + h * HD + dt * 32 + l31] = f2bf(oacc1[dt][r] * iq1);
    }
  }
}

// ---------------- launch ----------------
extern "C" void kernel_launch(void* const* d_in, const int* in_sizes, int n_in,
                              void* d_out, int out_size, void* d_ws, size_t ws_size,
                              hipStream_t stream) {
  (void)in_sizes; (void)n_in; (void)out_size; (void)ws_size;
  const float* x  = (const float*)d_in[0];
  const float* Wq = (const float*)d_in[1];
  const float* bq = (const float*)d_in[2];
  const float* Wk = (const float*)d_in[3];
  const float* bk = (const float*)d_in[4];
  const float* Wv = (const float*)d_in[5];
  const float* bv = (const float*)d_in[6];
  const float* Wo = (const float*)d_in[7];
  const float* bo = (const float*)d_in[8];
  float* out = (float*)d_out;

  char* ws = (char*)d_ws;
  const size_t SZ = (size_t)BATCH * NSEQ * EMB * 2;  // bytes per bf16 activation buffer
  u16* XB = (u16*)(ws);            // x bf16; later reused as VT
  u16* QB = (u16*)(ws + SZ);
  u16* KB = (u16*)(ws + 2 * SZ);
  u16* VB = (u16*)(ws + 3 * SZ);   // later reused as attn_out
  u16* WT = (u16*)(ws + 4 * SZ);   // 4 x 768*768 bf16
  u16* VT = XB;
  u16* AO = VB;

  k_prep<<<dim3(6144 + 2304), dim3(256), 0, stream>>>(x, XB, Wq, Wk, Wv, Wo, WT);
  k_qkv_gemm<<<dim3(64, 3, 3), dim3(512), 0, stream>>>(XB, WT, bq, bk, bv, QB, KB, VB);
  k_vtrans<<<dim3(16, 64), dim3(256), 0, stream>>>(VB, VT);
  k_attn<<<dim3(64, 8), dim3(256), 0, stream>>>(QB, KB, VT, AO);
  k_out_gemm<<<dim3(64, 3), dim3(512), 0, stream>>>(AO, WT + (size_t)3 * EMB * EMB, bo, out);
}